// Round 3
// baseline (155.622 us; speedup 1.0000x reference)
//
#include <hip/hip_runtime.h>
#include <stdint.h>

#define IN_F 4096
#define OUT_F 4096
#define NG 32

typedef __attribute__((ext_vector_type(8))) _Float16 half8;
typedef __attribute__((ext_vector_type(2))) _Float16 half2t;
typedef __attribute__((ext_vector_type(4))) float floatx4;

// ---------------------------------------------------------------------------
// Prep kernel: (a) convert x f32 -> fp16 with k-permuted pair layout,
//              (b) splat scale/zero into fp16x2 (s2, c2) table.
// k-permutation within each aligned 8-group: physical slot p holds logical
// k = (p&1)*4 + (p>>1), i.e. pairs (x0,x4),(x1,x5),(x2,x6),(x3,x7).
// The SAME permutation is produced by the in-gemm W dequant, so MFMA results
// are unchanged (A and B k-slots stay matched).
// ---------------------------------------------------------------------------
__global__ __launch_bounds__(256) void prep_kernel(
    const float* __restrict__ x, _Float16* __restrict__ Xh,
    const float* __restrict__ wscale, const int* __restrict__ wzero,
    uint2* __restrict__ SZ, int nxb) {
  int b = blockIdx.x;
  if (b < nxb) {
    int i = b * 256 + threadIdx.x;           // one 8-float group per thread
    const float4* x4 = (const float4*)x;
    float4 a = x4[2 * i];
    float4 c = x4[2 * i + 1];
    uint4 o;
    o.x = __builtin_bit_cast(unsigned, __builtin_amdgcn_cvt_pkrtz(a.x, c.x));  // (x0, x4)
    o.y = __builtin_bit_cast(unsigned, __builtin_amdgcn_cvt_pkrtz(a.y, c.y));  // (x1, x5)
    o.z = __builtin_bit_cast(unsigned, __builtin_amdgcn_cvt_pkrtz(a.z, c.z));  // (x2, x6)
    o.w = __builtin_bit_cast(unsigned, __builtin_amdgcn_cvt_pkrtz(a.w, c.w));  // (x3, x7)
    ((uint4*)Xh)[i] = o;
  } else {
    int i = (b - nxb) * 256 + threadIdx.x;   // 0 .. OUT_F*NG-1
    float s = wscale[i];
    int zp = wzero[i];
    _Float16 sh = (_Float16)s;
    _Float16 ch = (_Float16)(float)(1032 + zp);  // exact in fp16
    unsigned s2 = (unsigned)__builtin_bit_cast(unsigned short, sh) * 0x10001u;
    unsigned c2 = (unsigned)__builtin_bit_cast(unsigned short, ch) * 0x10001u;
    SZ[i] = make_uint2(s2, c2);
  }
}

// ---------------------------------------------------------------------------
// Fused W4A16 GEMM.  C[m][n] = sum_k A[m][k] * W[n][k]
// A: M x K fp16 (permuted-k), staged via global_load_lds (no VALU).
// W: packed int4, dequantized in-register to fp16 pairs:
//   h = fp16(1024 + (q^8))  via (nib | 0x6400);  w = (h - (1032+zp)) * s
// Tile 128x128, BK=64, 4 waves (each 64x64 -> acc[4][4], 32 MFMA/wave/kstep),
// SPLITK=2 -> grid 32*8*2 = 512 blocks = 2 blocks/CU, LDS 32 KB.
// Next-kstep packed-B + scale loads are register-prefetched before barrier 2
// so their latency hides under the MFMA phase.
// ---------------------------------------------------------------------------
#define BM 128
#define BN 128
#define BK 64
#define SPLITK 2

__device__ __forceinline__ uint4 dequant8(unsigned v, uint2 szv) {
  unsigned tx = v ^ 0x88888888u;
  half2t s2 = __builtin_bit_cast(half2t, szv.x);
  half2t c2 = __builtin_bit_cast(half2t, szv.y);
  unsigned p0 = (tx & 0x000F000Fu) | 0x64006400u;          // (n0, n4)
  unsigned p1 = ((tx >> 4) & 0x000F000Fu) | 0x64006400u;   // (n1, n5)
  unsigned p2 = ((tx >> 8) & 0x000F000Fu) | 0x64006400u;   // (n2, n6)
  unsigned p3 = ((tx >> 12) & 0x000F000Fu) | 0x64006400u;  // (n3, n7)
  half2t w0 = (__builtin_bit_cast(half2t, p0) - c2) * s2;
  half2t w1 = (__builtin_bit_cast(half2t, p1) - c2) * s2;
  half2t w2 = (__builtin_bit_cast(half2t, p2) - c2) * s2;
  half2t w3 = (__builtin_bit_cast(half2t, p3) - c2) * s2;
  uint4 o;
  o.x = __builtin_bit_cast(unsigned, w0);
  o.y = __builtin_bit_cast(unsigned, w1);
  o.z = __builtin_bit_cast(unsigned, w2);
  o.w = __builtin_bit_cast(unsigned, w3);
  return o;
}

__global__ __launch_bounds__(256) void gemm_fused(
    const _Float16* __restrict__ A, const int* __restrict__ wp,
    const uint2* __restrict__ SZ,
    float* __restrict__ C0, float* __restrict__ C1, int M, int N, int K) {
  __shared__ _Float16 Alds[BM * BK];  // 16 KB
  __shared__ _Float16 Blds[BN * BK];  // 16 KB

  int t = threadIdx.x;
  int wave = t >> 6, lane = t & 63;
  int wm = (wave >> 1) * 64, wn = (wave & 1) * 64;
  int r = lane & 15, quad = lane >> 4;
  int bm = blockIdx.y * BM, bn = blockIdx.x * BN;
  int kz = blockIdx.z * (K / SPLITK);
  int kend = kz + K / SPLITK;

  floatx4 acc[4][4] = {};

  const _Float16* Ag = A + (size_t)bm * K;

  // B staging: uint4 LDS index i (0..1023): row = i>>3 (8 uint4 per 64-fp16
  // row), int32 slot m = i&7.  Thread t handles i = t + 256*j, j=0..3
  // -> rows rowb + 32*j; ds_write addresses i*16 are linear (conflict-free).
  int rowb = t >> 3, m8 = t & 7;
  const int* wpr[4];
  const uint2* szp[4];
#pragma unroll
  for (int j = 0; j < 4; ++j) {
    wpr[j] = wp + (size_t)(bn + rowb + 32 * j) * (IN_F / 8) + m8;
    szp[j] = SZ + (size_t)(bn + rowb + 32 * j) * NG;
  }

  // Prologue: load packed B + scales for the first k-step.
  unsigned v[4];
  uint2 sz[4];
#pragma unroll
  for (int j = 0; j < 4; ++j) {
    v[j] = (unsigned)wpr[j][kz >> 3];
    sz[j] = szp[j][kz >> 7];
  }

  for (int k0 = kz; k0 < kend; k0 += BK) {
    __syncthreads();  // previous compute done before overwriting LDS

    // A: 128x64 fp16 = 1024 x 16B chunks, direct-to-LDS.
#pragma unroll
    for (int j = 0; j < 4; ++j) {
      int c = t + 256 * j;
      int row = c >> 3, kc = c & 7;
      const _Float16* ga = Ag + (size_t)row * K + k0 + kc * 8;
      __builtin_amdgcn_global_load_lds(
          (const __attribute__((address_space(1))) void*)ga,
          (__attribute__((address_space(3))) void*)(&Alds[c * 8]), 16, 0, 0);
    }

    // B: dequant current registers -> linear b128 LDS writes.
#pragma unroll
    for (int j = 0; j < 4; ++j)
      ((uint4*)Blds)[t + 256 * j] = dequant8(v[j], sz[j]);

    // Prefetch next k-step's packed B + scales; latency hides under MFMAs.
    int kn = (k0 + BK < kend) ? (k0 + BK) : k0;
    unsigned vn[4];
    uint2 szn[4];
#pragma unroll
    for (int j = 0; j < 4; ++j) {
      vn[j] = (unsigned)wpr[j][kn >> 3];
      szn[j] = szp[j][kn >> 7];
    }

    __syncthreads();  // drains vmcnt (A) + lgkmcnt (B)

#pragma unroll
    for (int ks = 0; ks < 2; ++ks) {
      int kk = ks * 32;
      half8 af[4], bf[4];
#pragma unroll
      for (int mi = 0; mi < 4; ++mi)
        af[mi] = *(const half8*)&Alds[(wm + mi * 16 + r) * BK + kk + quad * 8];
#pragma unroll
      for (int ni = 0; ni < 4; ++ni)
        bf[ni] = *(const half8*)&Blds[(wn + ni * 16 + r) * BK + kk + quad * 8];
#pragma unroll
      for (int mi = 0; mi < 4; ++mi)
#pragma unroll
        for (int ni = 0; ni < 4; ++ni)
          acc[mi][ni] = __builtin_amdgcn_mfma_f32_16x16x32_f16(
              af[mi], bf[ni], acc[mi][ni], 0, 0, 0);
    }

#pragma unroll
    for (int j = 0; j < 4; ++j) {
      v[j] = vn[j];
      sz[j] = szn[j];
    }
  }

  float* C = (blockIdx.z == 0) ? C0 : C1;
  // C/D layout: col = lane&15, row = quad*4 + reg
#pragma unroll
  for (int mi = 0; mi < 4; ++mi) {
#pragma unroll
    for (int ni = 0; ni < 4; ++ni) {
#pragma unroll
      for (int i = 0; i < 4; ++i) {
        int grow = bm + wm + mi * 16 + quad * 4 + i;
        int gcol = bn + wn + ni * 16 + r;
        C[(size_t)grow * N + gcol] = acc[mi][ni][i];
      }
    }
  }
}

__global__ __launch_bounds__(256) void reduce_kernel(
    float* __restrict__ out, const float* __restrict__ part) {
  int i = blockIdx.x * 256 + threadIdx.x;
  float4 a = ((const float4*)out)[i];
  float4 b = ((const float4*)part)[i];
  a.x += b.x; a.y += b.y; a.z += b.z; a.w += b.w;
  ((float4*)out)[i] = a;
}

extern "C" void kernel_launch(void* const* d_in, const int* in_sizes, int n_in,
                              void* d_out, int out_size, void* d_ws, size_t ws_size,
                              hipStream_t stream) {
  const float* x = (const float*)d_in[0];
  const int* wp = (const int*)d_in[1];
  const float* wscale = (const float*)d_in[2];
  const int* wzero = (const int*)d_in[3];
  float* out = (float*)d_out;

  int M = in_sizes[0] / IN_F;  // 1024

  // Workspace: Xh (fp16 M*K = 8.39 MB) | Cpart (f32 M*N = 16.78 MB) | SZ (1 MB)
  _Float16* Xh = (_Float16*)d_ws;
  float* Cpart = (float*)((char*)d_ws + (size_t)M * IN_F * 2);
  uint2* SZ = (uint2*)((char*)d_ws + (size_t)M * IN_F * 2 + (size_t)M * OUT_F * 4);

  int nxb = (M * IN_F / 8) / 256;       // 2048 blocks for x-convert
  int nzb = (OUT_F * NG) / 256;         // 512 blocks for scale/zero table
  prep_kernel<<<nxb + nzb, 256, 0, stream>>>(x, Xh, wscale, wzero, SZ, nxb);

  dim3 grid(OUT_F / BN, M / BM, SPLITK);  // (32, 8, 2) = 512 blocks
  gemm_fused<<<grid, 256, 0, stream>>>(Xh, wp, SZ, out, Cpart, M, OUT_F, IN_F);

  reduce_kernel<<<(M * OUT_F / 4) / 256, 256, 0, stream>>>(out, Cpart);
}

// Round 4
// 122.529 us; speedup vs baseline: 1.2701x; 1.2701x over previous
//
#include <hip/hip_runtime.h>
#include <stdint.h>

#define IN_F 4096
#define OUT_F 4096
#define NG 32

typedef __attribute__((ext_vector_type(8))) _Float16 half8;
typedef __attribute__((ext_vector_type(2))) _Float16 half2t;
typedef __attribute__((ext_vector_type(4))) float floatx4;

// ---------------------------------------------------------------------------
// Prep kernel: (a) convert x f32 -> fp16 with k-permuted pair layout,
//              (b) splat scale/zero into fp16x2 (s2, c2) table.
// k-permutation within each aligned 8-group: physical slot p holds logical
// k = (p&1)*4 + (p>>1), i.e. pairs (x0,x4),(x1,x5),(x2,x6),(x3,x7).
// The SAME permutation is produced by the in-gemm W dequant, so MFMA results
// are unchanged (A and B k-slots stay matched).
// ---------------------------------------------------------------------------
__global__ __launch_bounds__(256) void prep_kernel(
    const float* __restrict__ x, _Float16* __restrict__ Xh,
    const float* __restrict__ wscale, const int* __restrict__ wzero,
    uint2* __restrict__ SZ, int nxb) {
  int b = blockIdx.x;
  if (b < nxb) {
    int i = b * 256 + threadIdx.x;           // one 8-float group per thread
    const float4* x4 = (const float4*)x;
    float4 a = x4[2 * i];
    float4 c = x4[2 * i + 1];
    uint4 o;
    o.x = __builtin_bit_cast(unsigned, __builtin_amdgcn_cvt_pkrtz(a.x, c.x));  // (x0, x4)
    o.y = __builtin_bit_cast(unsigned, __builtin_amdgcn_cvt_pkrtz(a.y, c.y));  // (x1, x5)
    o.z = __builtin_bit_cast(unsigned, __builtin_amdgcn_cvt_pkrtz(a.z, c.z));  // (x2, x6)
    o.w = __builtin_bit_cast(unsigned, __builtin_amdgcn_cvt_pkrtz(a.w, c.w));  // (x3, x7)
    ((uint4*)Xh)[i] = o;
  } else {
    int i = (b - nxb) * 256 + threadIdx.x;   // 0 .. OUT_F*NG-1
    float s = wscale[i];
    int zp = wzero[i];
    _Float16 sh = (_Float16)s;
    _Float16 ch = (_Float16)(float)(1032 + zp);  // exact in fp16
    unsigned s2 = (unsigned)__builtin_bit_cast(unsigned short, sh) * 0x10001u;
    unsigned c2 = (unsigned)__builtin_bit_cast(unsigned short, ch) * 0x10001u;
    SZ[i] = make_uint2(s2, c2);
  }
}

// ---------------------------------------------------------------------------
// Fused W4A16 GEMM, single-barrier double-buffered pipeline, in-block split-K.
//   C[m][n] = sum_k A[m][k] * W[n][k]
// 512 threads = 8 waves: waves 0-3 compute k [0,2048), waves 4-7 k [2048,4096);
// each wave owns a 64x64 output subtile (acc[4][4], 32 MFMA / k-step).
// Per k-step: stage A(k+1) via global_load_lds + dequant-write B(k+1) into the
// other LDS buffer, THEN run MFMAs on the current buffer, then ONE barrier.
// Staging latency + dequant VALU hide under the MFMA phase.
// LDS: A[2 halves][2 bufs][128x64] + B same = 128 KB -> 1 block/CU, 8 waves.
// Chunk swizzle (T2-lite): LDS slot (row, kc) holds logical chunk kc^(row&7).
// A: applied on the GLOBAL source address (LDS dest must stay lane-linear for
// global_load_lds); B: applied on the ds_write address. Reads apply the same
// XOR. Involution => consistent; logical k-slots of A and B stay matched.
// Epilogue: half-1 waves dump acc into LDS (reusing A region), half-0 waves
// add and store C directly -> no split-K reduce kernel, no partial buffer.
// ---------------------------------------------------------------------------
#define NSTEP 32   // (K/2)/64 k-steps per half

__device__ __forceinline__ uint4 dequant8(unsigned v, uint2 szv) {
  unsigned tx = v ^ 0x88888888u;
  half2t s2 = __builtin_bit_cast(half2t, szv.x);
  half2t c2 = __builtin_bit_cast(half2t, szv.y);
  unsigned p0 = (tx & 0x000F000Fu) | 0x64006400u;          // (n0, n4)
  unsigned p1 = ((tx >> 4) & 0x000F000Fu) | 0x64006400u;   // (n1, n5)
  unsigned p2 = ((tx >> 8) & 0x000F000Fu) | 0x64006400u;   // (n2, n6)
  unsigned p3 = ((tx >> 12) & 0x000F000Fu) | 0x64006400u;  // (n3, n7)
  half2t w0 = (__builtin_bit_cast(half2t, p0) - c2) * s2;
  half2t w1 = (__builtin_bit_cast(half2t, p1) - c2) * s2;
  half2t w2 = (__builtin_bit_cast(half2t, p2) - c2) * s2;
  half2t w3 = (__builtin_bit_cast(half2t, p3) - c2) * s2;
  uint4 o;
  o.x = __builtin_bit_cast(unsigned, w0);
  o.y = __builtin_bit_cast(unsigned, w1);
  o.z = __builtin_bit_cast(unsigned, w2);
  o.w = __builtin_bit_cast(unsigned, w3);
  return o;
}

__global__ __launch_bounds__(512, 2) void gemm_fused(
    const _Float16* __restrict__ A, const int* __restrict__ wp,
    const uint2* __restrict__ SZ, float* __restrict__ out,
    int M, int N, int K) {
  __shared__ __align__(16) _Float16 Alds[4 * 8192];  // [half*2+buf][128*64] 64 KB
  __shared__ __align__(16) _Float16 Blds[4 * 8192];  // 64 KB

  int t = threadIdx.x;
  int wave = t >> 6, lane = t & 63;
  int h = wave >> 2, w2 = wave & 3;
  int wm = (w2 >> 1) * 64, wn = (w2 & 1) * 64;
  int r = lane & 15, quad = lane >> 4, rb = r & 7;
  int bm = blockIdx.y * 128, bn = blockIdx.x * 128;

  floatx4 acc[4][4] = {};

  // ---- staging geometry: chunk j=0..3 covers both halves' A and B tiles ----
  // c = t + 512*j; half_j = j>>1; cc = t + 512*(j&1); row = cc>>3; kc = t&7.
  int kc = t & 7;
  int row0 = t >> 3;           // j&1 == 0
  int row1 = row0 + 64;        // j&1 == 1  (row1&7 == row0&7)
  int gkc = kc ^ (row0 & 7);   // swizzled source chunk (same for both rows)

  const _Float16* Ag = A + (size_t)bm * K;
  const _Float16* gA[4];
  gA[0] = Ag + (size_t)row0 * K + gkc * 8;          // half 0
  gA[1] = Ag + (size_t)row1 * K + gkc * 8;          // half 0
  gA[2] = gA[0] + 2048;                             // half 1
  gA[3] = gA[1] + 2048;

  const int* gB[4];
  const uint2* gS[4];
  gB[0] = wp + (size_t)(bn + row0) * (IN_F / 8) + kc;
  gB[1] = wp + (size_t)(bn + row1) * (IN_F / 8) + kc;
  gB[2] = gB[0] + 256;                              // half 1 (+2048 fp16 = +256 int32)
  gB[3] = gB[1] + 256;
  gS[0] = SZ + (size_t)(bn + row0) * NG;
  gS[1] = SZ + (size_t)(bn + row1) * NG;
  gS[2] = gS[0] + 16;                               // half 1 (+16 groups)
  gS[3] = gS[1] + 16;

  int bslot = gkc << 3;                             // swizzled B write slot (fp16)
  int bofs0 = row0 * 64 + bslot;
  int bofs1 = row1 * 64 + bslot;

  auto STAGE_A = [&](int i, int buf) {
#pragma unroll
    for (int j = 0; j < 4; ++j) {
      const _Float16* src = gA[j] + i * 64;
      int dst = ((j >> 1) * 2 + buf) * 8192 + (t + 512 * (j & 1)) * 8;
      __builtin_amdgcn_global_load_lds(
          (const __attribute__((address_space(1))) void*)src,
          (__attribute__((address_space(3))) void*)(&Alds[dst]), 16, 0, 0);
    }
  };
  auto STAGE_B = [&](const unsigned* v, const uint2* sz, int buf) {
#pragma unroll
    for (int j = 0; j < 4; ++j) {
      int ofs = ((j >> 1) * 2 + buf) * 8192 + ((j & 1) ? bofs1 : bofs0);
      *(uint4*)&Blds[ofs] = dequant8(v[j], sz[j]);
    }
  };
  auto LOADV = [&](int i, unsigned* v, uint2* sz) {
#pragma unroll
    for (int j = 0; j < 4; ++j) {
      v[j] = (unsigned)gB[j][i * 8];
      sz[j] = gS[j][i >> 1];
    }
  };

  // ---- prologue: fill buffer 0 for step 0, prefetch regs for step 1 ----
  unsigned v[4];
  uint2 sz[4];
  LOADV(0, v, sz);
  STAGE_A(0, 0);
  STAGE_B(v, sz, 0);
  LOADV(1, v, sz);
  __syncthreads();   // drains A(0) vmcnt + B(0) lgkm

  int cur = 0;
  for (int i = 0; i < NSTEP; ++i) {
    int nxt = cur ^ 1;
    if (i + 1 < NSTEP) {
      STAGE_A(i + 1, nxt);               // async DMA, hides under MFMAs below
      STAGE_B(v, sz, nxt);               // dequant VALU + ds_write, other buffer
      int i2 = (i + 2 < NSTEP) ? (i + 2) : (NSTEP - 1);
      LOADV(i2, v, sz);                  // packed/scale regs for next staging
    }

    const _Float16* Ab = &Alds[(h * 2 + cur) * 8192];
    const _Float16* Bb = &Blds[(h * 2 + cur) * 8192];
#pragma unroll
    for (int ks = 0; ks < 2; ++ks) {
      half8 af[4], bf[4];
#pragma unroll
      for (int mi = 0; mi < 4; ++mi) {
        int R = wm + mi * 16 + r;        // R&7 == rb
        af[mi] = *(const half8*)&Ab[R * 64 + (((ks * 4 + quad) ^ rb) << 3)];
      }
#pragma unroll
      for (int ni = 0; ni < 4; ++ni) {
        int R = wn + ni * 16 + r;
        bf[ni] = *(const half8*)&Bb[R * 64 + (((ks * 4 + quad) ^ rb) << 3)];
      }
#pragma unroll
      for (int mi = 0; mi < 4; ++mi)
#pragma unroll
        for (int ni = 0; ni < 4; ++ni)
          acc[mi][ni] = __builtin_amdgcn_mfma_f32_16x16x32_f16(
              af[mi], bf[ni], acc[mi][ni], 0, 0, 0);
    }
    __syncthreads();   // all waves done with cur; nxt fully staged (vmcnt+lgkm)
    cur = nxt;
  }

  // ---- in-block split-K reduction (reuse A LDS region, 64 KB) ----
  floatx4* red = (floatx4*)Alds;
  if (h == 1) {
#pragma unroll
    for (int mi = 0; mi < 4; ++mi)
#pragma unroll
      for (int ni = 0; ni < 4; ++ni)
        red[(mi * 4 + ni) * 256 + w2 * 64 + lane] = acc[mi][ni];
  }
  __syncthreads();
  if (h == 0) {
#pragma unroll
    for (int mi = 0; mi < 4; ++mi) {
#pragma unroll
      for (int ni = 0; ni < 4; ++ni) {
        acc[mi][ni] += red[(mi * 4 + ni) * 256 + w2 * 64 + lane];
#pragma unroll
        for (int i = 0; i < 4; ++i) {
          int grow = bm + wm + mi * 16 + quad * 4 + i;
          int gcol = bn + wn + ni * 16 + r;
          out[(size_t)grow * N + gcol] = acc[mi][ni][i];
        }
      }
    }
  }
}

extern "C" void kernel_launch(void* const* d_in, const int* in_sizes, int n_in,
                              void* d_out, int out_size, void* d_ws, size_t ws_size,
                              hipStream_t stream) {
  const float* x = (const float*)d_in[0];
  const int* wp = (const int*)d_in[1];
  const float* wscale = (const float*)d_in[2];
  const int* wzero = (const int*)d_in[3];
  float* out = (float*)d_out;

  int M = in_sizes[0] / IN_F;  // 1024

  // Workspace: Xh (fp16 M*K = 8.39 MB) | SZ (1 MB)
  _Float16* Xh = (_Float16*)d_ws;
  uint2* SZ = (uint2*)((char*)d_ws + (size_t)M * IN_F * 2);

  int nxb = (M * IN_F / 8) / 256;       // 2048 blocks for x-convert
  int nzb = (OUT_F * NG) / 256;         // 512 blocks for scale/zero table
  prep_kernel<<<nxb + nzb, 256, 0, stream>>>(x, Xh, wscale, wzero, SZ, nxb);

  dim3 grid(OUT_F / 128, M / 128);      // (32, 8) = 256 blocks, 1/CU
  gemm_fused<<<grid, 512, 0, stream>>>(Xh, wp, SZ, out, M, OUT_F, IN_F);
}